// Round 5
// baseline (118.469 us; speedup 1.0000x reference)
//
#include <hip/hip_runtime.h>

#define BATCH 8
#define CIN 64
#define H 128
#define W 128
#define OCH 64
#define HW (H*W)
#define OFFCH 18

using f16x8 = __attribute__((ext_vector_type(8))) _Float16;
using f32x4 = __attribute__((ext_vector_type(4))) float;

static __device__ __forceinline__ int iclamp(int v, int lo, int hi) {
    return v < lo ? lo : (v > hi ? hi : v);
}
static __device__ __forceinline__ f16x8 splat8(_Float16 v) {
    return (f16x8){v, v, v, v, v, v, v, v};
}

// ---------------- transpose x [B][C][H][W] f32 -> xt [B][H][W][C] f16 ----------------
__global__ __launch_bounds__(256) void transpose_x_kernel(
    const float* __restrict__ x, _Float16* __restrict__ xt)
{
    __shared__ float ls[CIN][129];
    int bid = blockIdx.x;          // B*H = 1024
    int b = bid >> 7, y = bid & 127;
    int t = threadIdx.x;

    const float* xb = x + (size_t)b * CIN * HW + (size_t)y * W;
    #pragma unroll 4
    for (int i = 0; i < 32; ++i) {
        int c = i * 2 + (t >> 7);
        ls[c][t & 127] = xb[(size_t)c * HW + (t & 127)];
    }
    __syncthreads();

    _Float16* xo = xt + (size_t)(b * H + y) * W * CIN;
    #pragma unroll 4
    for (int i = 0; i < 16; ++i) {
        int px = i * 8 + (t >> 5);
        int c  = (t & 31) * 2;
        _Float16 a0 = (_Float16)ls[c][px];
        _Float16 a1 = (_Float16)ls[c + 1][px];
        union { _Float16 h[2]; unsigned int u; } pk;
        pk.h[0] = a0; pk.h[1] = a1;
        *(unsigned int*)&xo[(size_t)px * CIN + c] = pk.u;
    }
}

// ---------------- prep w_deform -> f16 MFMA A-frag order ----------------
__global__ __launch_bounds__(256) void prep_wdf_kernel(
    const float* __restrict__ w, _Float16* __restrict__ wdf)
{
    int i = blockIdx.x * 256 + threadIdx.x;   // 9*2*4*64*8 = 36864
    if (i >= 9 * 2 * 4 * 64 * 8) return;
    int j    = i & 7;
    int lane = (i >> 3) & 63;
    int mt   = (i >> 9) & 3;
    int cs   = (i >> 11) & 1;
    int tap  = i >> 12;
    int oc = mt * 16 + (lane & 15);
    int c  = cs * 32 + (lane >> 4) * 8 + j;
    wdf[i] = (_Float16)w[(oc * CIN + c) * 9 + tap];
}

// ---------------- prep w_offset -> f16 MFMA A-frag order (M padded 18->32) ----------------
__global__ __launch_bounds__(256) void prep_wof_kernel(
    const float* __restrict__ w, _Float16* __restrict__ wof)
{
    int i = blockIdx.x * 256 + threadIdx.x;   // 9*2*2*64*8 = 18432
    if (i >= 9 * 2 * 2 * 64 * 8) return;
    int j    = i & 7;
    int lane = (i >> 3) & 63;
    int mt   = (i >> 9) & 1;
    int cs   = (i >> 10) & 1;
    int tap  = i >> 11;
    int oc = mt * 16 + (lane & 15);
    int c  = cs * 32 + (lane >> 4) * 8 + j;
    wof[i] = (oc < OFFCH) ? (_Float16)w[(oc * CIN + c) * 9 + tap] : (_Float16)0.f;
}

// ---------------- fused offset-conv + deformable conv ----------------
// Block=(b,y), 4 waves x 32 px. Phase 1: offset GEMM -> LDS. Phase 2: deform GEMM.
__global__ __launch_bounds__(256, 4) void fused_deform_kernel(
    const _Float16* __restrict__ xt, const f16x8* __restrict__ wof,
    const f16x8* __restrict__ wdf, const float* __restrict__ bias,
    float* __restrict__ out)
{
    __shared__ float offs[4][32][19];   // [wave][pix][oc], stride 19 -> conflict-free reads

    int bid  = blockIdx.x;           // 1024
    int b    = bid & 7;              // one batch per XCD
    int y    = bid >> 3;
    int tid  = threadIdx.x;
    int lane = tid & 63;
    int wave = tid >> 6;
    int l15  = lane & 15;
    int lk   = lane >> 4;
    int pixbase = wave * 32;

    const _Float16* xb = xt + (size_t)b * HW * CIN;

    // ======== phase 1: offset conv (M=32 padded, N=32/wave, K=576) ========
    {
        f32x4 oacc[2][2];
        #pragma unroll
        for (int mt = 0; mt < 2; ++mt)
            #pragma unroll
            for (int nt = 0; nt < 2; ++nt) oacc[mt][nt] = (f32x4){0.f, 0.f, 0.f, 0.f};

        #pragma unroll 3
        for (int tap = 0; tap < 9; ++tap) {
            int ky = tap / 3, kx = tap - 3 * ky;
            int yy = y - 1 + ky;
            #pragma unroll
            for (int cs = 0; cs < 2; ++cs) {
                f16x8 afrag[2];
                const f16x8* wf = wof + (size_t)((tap * 2 + cs) * 2) * 64 + lane;
                #pragma unroll
                for (int mt = 0; mt < 2; ++mt) afrag[mt] = wf[mt * 64];

                #pragma unroll
                for (int nt = 0; nt < 2; ++nt) {
                    int pos = pixbase + nt * 16 + l15 - 1 + kx;
                    f16x8 bfrag = splat8((_Float16)0.f);
                    if (yy >= 0 && yy < H && pos >= 0 && pos < W)
                        bfrag = *(const f16x8*)&xb[((size_t)yy * W + pos) * CIN + cs * 32 + lk * 8];
                    #pragma unroll
                    for (int mt = 0; mt < 2; ++mt)
                        oacc[mt][nt] = __builtin_amdgcn_mfma_f32_16x16x32_f16(
                            afrag[mt], bfrag, oacc[mt][nt], 0, 0, 0);
                }
            }
        }

        #pragma unroll
        for (int mt = 0; mt < 2; ++mt)
            #pragma unroll
            for (int nt = 0; nt < 2; ++nt)
                #pragma unroll
                for (int r = 0; r < 4; ++r) {
                    int oc = mt * 16 + lk * 4 + r;
                    if (oc < OFFCH)
                        offs[wave][nt * 16 + l15][oc] = oacc[mt][nt][r];
                }
    }
    __syncthreads();

    // ======== phase 2: deformable conv (M=64, N=32/wave, K=576) ========
    f32x4 acc[4][2];
    #pragma unroll
    for (int mt = 0; mt < 4; ++mt)
        #pragma unroll
        for (int nt = 0; nt < 2; ++nt) acc[mt][nt] = (f32x4){0.f, 0.f, 0.f, 0.f};

    #pragma unroll 3
    for (int tap = 0; tap < 9; ++tap) {
        int ky = tap / 3, kx = tap - 3 * ky;

        _Float16 h00[2], h01[2], h10[2], h11[2];
        int i00[2], i01[2], i10[2], i11[2];
        #pragma unroll
        for (int nt = 0; nt < 2; ++nt) {
            int ploc = nt * 16 + l15;
            int p    = pixbase + ploc;
            float offy = offs[wave][ploc][2 * tap];
            float offx = offs[wave][ploc][2 * tap + 1];
            float py = (float)(y - 1 + ky) + offy;
            float px = (float)(p - 1 + kx) + offx;
            float y0f = floorf(py), x0f = floorf(px);
            float fy = py - y0f, fx = px - x0f;
            int y0 = (int)y0f, x0 = (int)x0f;
            int y1 = y0 + 1, x1 = x0 + 1;
            float m00 = (1.f - fy) * (1.f - fx);
            float m01 = (1.f - fy) * fx;
            float m10 = fy * (1.f - fx);
            float m11 = fy * fx;
            if (y0 < 0 || y0 >= H) { m00 = 0.f; m01 = 0.f; }
            if (y1 < 0 || y1 >= H) { m10 = 0.f; m11 = 0.f; }
            if (x0 < 0 || x0 >= W) { m00 = 0.f; m10 = 0.f; }
            if (x1 < 0 || x1 >= W) { m01 = 0.f; m11 = 0.f; }
            int y0c = iclamp(y0, 0, H - 1), y1c = iclamp(y1, 0, H - 1);
            int x0c = iclamp(x0, 0, W - 1), x1c = iclamp(x1, 0, W - 1);
            h00[nt] = (_Float16)m00; h01[nt] = (_Float16)m01;
            h10[nt] = (_Float16)m10; h11[nt] = (_Float16)m11;
            i00[nt] = (y0c * W + x0c) * CIN; i01[nt] = (y0c * W + x1c) * CIN;
            i10[nt] = (y1c * W + x0c) * CIN; i11[nt] = (y1c * W + x1c) * CIN;
        }

        #pragma unroll
        for (int cs = 0; cs < 2; ++cs) {
            f16x8 afrag[4];
            const f16x8* wf = wdf + (size_t)((tap * 2 + cs) * 4) * 64 + lane;
            #pragma unroll
            for (int mt = 0; mt < 4; ++mt) afrag[mt] = wf[mt * 64];

            int coff = cs * 32 + lk * 8;
            #pragma unroll
            for (int nt = 0; nt < 2; ++nt) {
                f16x8 g00 = *(const f16x8*)&xb[i00[nt] + coff];
                f16x8 g01 = *(const f16x8*)&xb[i01[nt] + coff];
                f16x8 g10 = *(const f16x8*)&xb[i10[nt] + coff];
                f16x8 g11 = *(const f16x8*)&xb[i11[nt] + coff];
                f16x8 bfrag = g00 * splat8(h00[nt]) + g01 * splat8(h01[nt])
                            + g10 * splat8(h10[nt]) + g11 * splat8(h11[nt]);
                #pragma unroll
                for (int mt = 0; mt < 4; ++mt)
                    acc[mt][nt] = __builtin_amdgcn_mfma_f32_16x16x32_f16(
                        afrag[mt], bfrag, acc[mt][nt], 0, 0, 0);
            }
        }
    }

    #pragma unroll
    for (int mt = 0; mt < 4; ++mt) {
        #pragma unroll
        for (int nt = 0; nt < 2; ++nt) {
            int p = pixbase + nt * 16 + l15;
            #pragma unroll
            for (int r = 0; r < 4; ++r) {
                int oc = mt * 16 + lk * 4 + r;
                out[((size_t)b * OCH + oc) * HW + (size_t)y * W + p] = acc[mt][nt][r] + bias[oc];
            }
        }
    }
}

extern "C" void kernel_launch(void* const* d_in, const int* in_sizes, int n_in,
                              void* d_out, int out_size, void* d_ws, size_t ws_size,
                              hipStream_t stream) {
    const float* x     = (const float*)d_in[0];
    const float* w_off = (const float*)d_in[1];
    const float* w_def = (const float*)d_in[2];
    const float* b_def = (const float*)d_in[3];
    float* out = (float*)d_out;

    _Float16* xt  = (_Float16*)d_ws;                 // 8.4M f16 (16.8 MB)
    _Float16* wdf = xt + (size_t)BATCH * HW * CIN;   // 36,864 f16
    _Float16* wof = wdf + 36864;                     // 18,432 f16

    transpose_x_kernel<<<BATCH * H, 256, 0, stream>>>(x, xt);
    prep_wdf_kernel<<<(36864 + 255) / 256, 256, 0, stream>>>(w_def, wdf);
    prep_wof_kernel<<<(18432 + 255) / 256, 256, 0, stream>>>(w_off, wof);
    fused_deform_kernel<<<BATCH * H, 256, 0, stream>>>(
        xt, (const f16x8*)wof, (const f16x8*)wdf, b_def, out);
}